// Round 1
// baseline (467.460 us; speedup 1.0000x reference)
//
#include <hip/hip_runtime.h>
#include <stdint.h>

#define B_   4
#define T_   32
#define N_   4096
#define F_   16
#define G_   64      // B*F
#define M_   128
#define K_   32
#define C0_  64
#define C1_  128

// ---------------------------------------------------------------------------
// Kernel 1: Furthest Point Sampling. One block per group g (64 blocks).
// Each thread owns 16 points (p = j*256 + t). Bit-exact fp32, no FMA contract.
// Writes anchor coords to ws (for ball query / MLP) and to d_out (new_xyzs).
// ---------------------------------------------------------------------------
__global__ __launch_bounds__(256) void fps_kernel(const float* __restrict__ xyzs,
                                                  float* __restrict__ anchors,
                                                  float* __restrict__ out_xyz)
{
#pragma clang fp contract(off)
    const int g = blockIdx.x;
    const int b = g >> 4, f = g & 15;
    const float* base = xyzs + ((size_t)(b * T_ + 2 * f) * N_) * 3;
    const int t = threadIdx.x;
    const int lane = t & 63;
    const int wid = t >> 6;

    float x[16], y[16], z[16], dist[16];
#pragma unroll
    for (int j = 0; j < 16; ++j) {
        int p = j * 256 + t;
        x[j] = base[p * 3 + 0];
        y[j] = base[p * 3 + 1];
        z[j] = base[p * 3 + 2];
        dist[j] = 1e10f;
    }

    __shared__ float bxyz[3];
    __shared__ float sd[4];
    __shared__ int   si[4];

    int cur = 0;
    for (int it = 0; it < M_; ++it) {
        // owner of `cur` publishes its coords and writes anchor slot `it`
        if (t == (cur & 255)) {
            int j = cur >> 8;
            bxyz[0] = x[j]; bxyz[1] = y[j]; bxyz[2] = z[j];
            size_t ao = ((size_t)g * M_ + it) * 3;
            anchors[ao + 0] = x[j]; anchors[ao + 1] = y[j]; anchors[ao + 2] = z[j];
            out_xyz[ao + 0] = x[j]; out_xyz[ao + 1] = y[j]; out_xyz[ao + 2] = z[j];
        }
        __syncthreads();
        if (it == M_ - 1) break;

        float px = bxyz[0], py = bxyz[1], pz = bxyz[2];
        float bd = -1.0f;
        int   bi = N_;
#pragma unroll
        for (int j = 0; j < 16; ++j) {
            float dx = x[j] - px;
            float dy = y[j] - py;
            float dz = z[j] - pz;
            float d = dx * dx + dy * dy;   // contract off: plain mul/add
            d = d + dz * dz;
            float nd = fminf(dist[j], d);
            dist[j] = nd;
            if (nd > bd) { bd = nd; bi = j * 256 + t; }   // ascending p -> first-max kept
        }
        // wave-level argmax reduce with first-index tie-break
#pragma unroll
        for (int off = 32; off > 0; off >>= 1) {
            float od = __shfl_xor(bd, off);
            int   oi = __shfl_xor(bi, off);
            if (od > bd || (od == bd && oi < bi)) { bd = od; bi = oi; }
        }
        if (lane == 0) { sd[wid] = bd; si[wid] = bi; }
        __syncthreads();
        // every thread combines the 4 wave results identically
        float cd = sd[0]; int ci = si[0];
#pragma unroll
        for (int w = 1; w < 4; ++w) {
            float od = sd[w]; int oi = si[w];
            if (od > cd || (od == cd && oi < ci)) { cd = od; ci = oi; }
        }
        cur = ci;
    }
}

// ---------------------------------------------------------------------------
// Kernel 2: Ball query. One wave per (g, dt, m): 24576 waves, 4 per block.
// Scan points in index order, pack first K=32 with d2 < R^2 (PointNet++ fill).
// ---------------------------------------------------------------------------
__global__ __launch_bounds__(256) void ballq_kernel(const float* __restrict__ xyzs,
                                                    const float* __restrict__ anchors,
                                                    int* __restrict__ widx)
{
#pragma clang fp contract(off)
    const float R2 = 0.0225f;
    const int wave = (blockIdx.x << 2) + (threadIdx.x >> 6);
    const int lane = threadIdx.x & 63;
    const int m   = wave % M_;
    const int gd  = wave / M_;      // g*3 + dti
    const int dti = gd % 3;
    const int g   = gd / 3;
    const int b = g >> 4, f = g & 15;
    int tn = 2 * f + dti - 1;
    if (tn < 0) tn = 0;             // upper clamp never triggers (max 31)
    const float* nb = xyzs + ((size_t)(b * T_ + tn) * N_) * 3;
    const float* aw = anchors + ((size_t)g * M_ + m) * 3;
    const float ax = aw[0], ay = aw[1], az = aw[2];

    __shared__ int sbuf[4][K_];
    int* buf = sbuf[threadIdx.x >> 6];

    int filled = 0;
    for (int itb = 0; itb < 64 && filled < K_; ++itb) {
        int p = itb * 64 + lane;
        float dx = nb[p * 3 + 0] - ax;
        float dy = nb[p * 3 + 1] - ay;
        float dz = nb[p * 3 + 2] - az;
        float d2 = dx * dx + dy * dy;
        d2 = d2 + dz * dz;
        bool valid = d2 < R2;
        unsigned long long mask = __ballot(valid);
        if (valid) {
            int slot = filled + __popcll(mask & ((1ULL << lane) - 1ULL));
            if (slot < K_) buf[slot] = p;
        }
        filled += __popcll(mask);
    }
    __syncthreads();   // all 4 waves of the block reach this (different iter counts ok)
    if (lane < K_) {
        int first = (filled > 0) ? buf[0] : 0;
        int v = (lane < filled) ? buf[lane] : first;
        widx[(size_t)wave * K_ + lane] = v;
    }
}

// ---------------------------------------------------------------------------
// Kernel 3: grouped MLP (4->64->128) + relu + max over K + sum over dt.
// One block (256 thr) per (g, m). Wm transposed in LDS [i][o]; h1 transposed
// [i][k]; per-thread 4k x 4o register tile: 2 ds_read_b128 per 16 FMA.
// ---------------------------------------------------------------------------
__global__ __launch_bounds__(256) void mlp_kernel(const float* __restrict__ xyzs,
                                                  const float* __restrict__ Wd,
                                                  const float* __restrict__ Wm,
                                                  const float* __restrict__ anchors,
                                                  const int* __restrict__ widx,
                                                  float* __restrict__ out_feat)
{
    const int t  = threadIdx.x;
    const int gm = blockIdx.x;
    const int g  = gm >> 7;
    const int m  = gm & 127;
    const int b = g >> 4, f = g & 15;

    __shared__ __align__(16) float wmt[C0_][C1_];   // 32 KB [i][o]
    __shared__ __align__(16) float h1t[C0_][K_];    // 8 KB  [i][k]
    __shared__ float wd_s[C0_ * 4];                 // 1 KB
    __shared__ float d4[K_][4];
    __shared__ __align__(16) float pm[8][C1_];      // 4 KB  [kg][o]
    __shared__ float anc[3];

    // stage Wm transposed (L2-resident, tiny)
    {
        int o = t >> 1;
        int i0 = (t & 1) * 32;
#pragma unroll 8
        for (int j = 0; j < 32; ++j)
            wmt[i0 + j][o] = Wm[o * C0_ + i0 + j];
    }
    wd_s[t] = Wd[t & 255];
    if (t < 3) anc[t] = anchors[((size_t)g * M_ + m) * 3 + t];
    __syncthreads();

    const int oq = t & 31;   // o quad: outputs oq*4 .. +3
    const int kg = t >> 5;   // k group: ks kg*4 .. +3
    float featsum = 0.0f;    // valid on t < 128 (o = t)

    for (int dti = 0; dti < 3; ++dti) {
        int tn = 2 * f + dti - 1;
        if (tn < 0) tn = 0;
        const float* nb = xyzs + ((size_t)(b * T_ + tn) * N_) * 3;
        if (t < K_) {
            int idx = widx[((size_t)(g * 3 + dti) * M_ + m) * K_ + t];
            d4[t][0] = nb[idx * 3 + 0] - anc[0];
            d4[t][1] = nb[idx * 3 + 1] - anc[1];
            d4[t][2] = nb[idx * 3 + 2] - anc[2];
            d4[t][3] = (float)(dti - 1);
        }
        __syncthreads();

        // h1: thread t computes k = t&31, i = (t>>5)*8 .. +7
        {
            int k = t & 31;
            int i0 = (t >> 5) * 8;
            float a0 = d4[k][0], a1 = d4[k][1], a2 = d4[k][2], a3 = d4[k][3];
#pragma unroll
            for (int u = 0; u < 8; ++u) {
                int i = i0 + u;
                float s = a0 * wd_s[i * 4 + 0] + a1 * wd_s[i * 4 + 1];
                s = s + a2 * wd_s[i * 4 + 2];
                s = s + a3 * wd_s[i * 4 + 3];
                h1t[i][k] = fmaxf(s, 0.0f);
            }
        }
        __syncthreads();

        // h2: register tile acc[k-local][o-local]
        float acc[4][4];
#pragma unroll
        for (int a = 0; a < 4; ++a)
#pragma unroll
            for (int c = 0; c < 4; ++c) acc[a][c] = 0.0f;

#pragma unroll 8
        for (int i = 0; i < C0_; ++i) {
            float4 w4 = *reinterpret_cast<const float4*>(&wmt[i][oq * 4]);
            float4 h4 = *reinterpret_cast<const float4*>(&h1t[i][kg * 4]);
            acc[0][0] += h4.x * w4.x; acc[0][1] += h4.x * w4.y;
            acc[0][2] += h4.x * w4.z; acc[0][3] += h4.x * w4.w;
            acc[1][0] += h4.y * w4.x; acc[1][1] += h4.y * w4.y;
            acc[1][2] += h4.y * w4.z; acc[1][3] += h4.y * w4.w;
            acc[2][0] += h4.z * w4.x; acc[2][1] += h4.z * w4.y;
            acc[2][2] += h4.z * w4.z; acc[2][3] += h4.z * w4.w;
            acc[3][0] += h4.w * w4.x; acc[3][1] += h4.w * w4.y;
            acc[3][2] += h4.w * w4.z; acc[3][3] += h4.w * w4.w;
        }
        // relu(max) == max(relu) since relu monotone; partial max over this thread's 4 ks
        float4 pmx;
        pmx.x = fmaxf(fmaxf(fmaxf(acc[0][0], acc[1][0]), fmaxf(acc[2][0], acc[3][0])), 0.0f);
        pmx.y = fmaxf(fmaxf(fmaxf(acc[0][1], acc[1][1]), fmaxf(acc[2][1], acc[3][1])), 0.0f);
        pmx.z = fmaxf(fmaxf(fmaxf(acc[0][2], acc[1][2]), fmaxf(acc[2][2], acc[3][2])), 0.0f);
        pmx.w = fmaxf(fmaxf(fmaxf(acc[0][3], acc[1][3]), fmaxf(acc[2][3], acc[3][3])), 0.0f);
        *reinterpret_cast<float4*>(&pm[kg][oq * 4]) = pmx;
        __syncthreads();

        if (t < C1_) {
            float v = pm[0][t];
#pragma unroll
            for (int q = 1; q < 8; ++q) v = fmaxf(v, pm[q][t]);
            featsum += v;   // dt order -1, 0, +1 matches reference accumulation
        }
        __syncthreads();   // before reusing d4 / h1t / pm next dt
    }

    if (t < C1_) {
        out_feat[((size_t)g * C1_ + t) * M_ + m] = featsum;
    }
}

// ---------------------------------------------------------------------------
extern "C" void kernel_launch(void* const* d_in, const int* in_sizes, int n_in,
                              void* d_out, int out_size, void* d_ws, size_t ws_size,
                              hipStream_t stream)
{
    (void)in_sizes; (void)n_in; (void)out_size; (void)ws_size;
    const float* xyzs = (const float*)d_in[0];
    const float* Wd   = (const float*)d_in[1];
    const float* Wm   = (const float*)d_in[2];
    float* out = (float*)d_out;

    float* anchors = (float*)d_ws;                                   // G*M*3 floats
    int*   widx    = (int*)((char*)d_ws + (size_t)G_ * M_ * 3 * 4);  // G*3*M*K ints

    float* out_xyz  = out;             // (B,F,M,3) flat = (G,M,3)
    float* out_feat = out + G_ * M_ * 3; // (B,F,C1,M) flat = (G,C1,M)

    hipLaunchKernelGGL(fps_kernel,   dim3(G_),        dim3(256), 0, stream, xyzs, anchors, out_xyz);
    hipLaunchKernelGGL(ballq_kernel, dim3(G_ * 3 * M_ / 4), dim3(256), 0, stream, xyzs, anchors, widx);
    hipLaunchKernelGGL(mlp_kernel,   dim3(G_ * M_),   dim3(256), 0, stream, xyzs, Wd, Wm, anchors, widx, out_feat);
}

// Round 2
// 436.012 us; speedup vs baseline: 1.0721x; 1.0721x over previous
//
#include <hip/hip_runtime.h>
#include <stdint.h>

#define B_   4
#define T_   32
#define N_   4096
#define F_   16
#define G_   64      // B*F
#define M_   128
#define K_   32
#define C0_  64
#define C1_  128

typedef short  short8 __attribute__((ext_vector_type(8)));
typedef float  f32x4  __attribute__((ext_vector_type(4)));

static __device__ __forceinline__ short f2bf(float x) {
    union { float f; unsigned u; } v; v.f = x;
    unsigned r = (v.u + 0x7FFFu + ((v.u >> 16) & 1u)) >> 16;
    return (short)r;
}
static __device__ __forceinline__ float bf2f(short h) {
    union { float f; unsigned u; } v; v.u = ((unsigned)(unsigned short)h) << 16;
    return v.f;
}

// ---------------------------------------------------------------------------
// Kernel 0: split Wm (fp32 [128][64]) into hi/lo bf16, stored in the LDS
// layout mlp uses: element off = o*64 + ((chunk ^ (o&7))<<3) + e, chunk=i/8.
// ---------------------------------------------------------------------------
__global__ __launch_bounds__(256) void wsplit_kernel(const float* __restrict__ Wm,
                                                     short* __restrict__ Bhi_g,
                                                     short* __restrict__ Blo_g)
{
    int id = blockIdx.x * 256 + threadIdx.x;   // 0..1023
    int o = id >> 3, c = id & 7;
    const float* wp = Wm + o * C0_ + c * 8;
    short8 hv, lv;
#pragma unroll
    for (int e = 0; e < 8; ++e) {
        float v = wp[e];
        short h = f2bf(v);
        short l = f2bf(v - bf2f(h));
        hv[e] = h; lv[e] = l;
    }
    int dst = o * C0_ + ((c ^ (o & 7)) << 3);
    *reinterpret_cast<short8*>(&Bhi_g[dst]) = hv;
    *reinterpret_cast<short8*>(&Blo_g[dst]) = lv;
}

// ---------------------------------------------------------------------------
// Kernel 1: FPS, one block per group. ONE barrier per iteration: the argmax
// shuffle-reduce carries the winner's coords (5-value butterfly), cross-wave
// combine via parity-double-buffered LDS. Bit-exact fp32 (contract off).
// ---------------------------------------------------------------------------
__global__ __launch_bounds__(256) void fps_kernel(const float* __restrict__ xyzs,
                                                  float* __restrict__ anchors,
                                                  float* __restrict__ out_xyz)
{
#pragma clang fp contract(off)
    const int g = blockIdx.x;
    const int b = g >> 4, f = g & 15;
    const float* base = xyzs + ((size_t)(b * T_ + 2 * f) * N_) * 3;
    const int t = threadIdx.x;
    const int lane = t & 63;
    const int wid = t >> 6;

    float x[16], y[16], z[16], dist[16];
#pragma unroll
    for (int j = 0; j < 16; ++j) {
        int p = j * 256 + t;
        x[j] = base[p * 3 + 0];
        y[j] = base[p * 3 + 1];
        z[j] = base[p * 3 + 2];
        dist[j] = 1e10f;
    }

    __shared__ float sd[2][4], sx[2][4], sy[2][4], sz[2][4];
    __shared__ int   si[2][4];

    float px = base[0], py = base[1], pz = base[2];
    if (t == 0) {
        size_t ao = (size_t)g * M_ * 3;
        anchors[ao + 0] = px; anchors[ao + 1] = py; anchors[ao + 2] = pz;
        out_xyz[ao + 0] = px; out_xyz[ao + 1] = py; out_xyz[ao + 2] = pz;
    }

    for (int it = 1; it < M_; ++it) {
        float bd = -1.0f; int bi = 0;
        float bx = 0.f, by = 0.f, bz = 0.f;
#pragma unroll
        for (int j = 0; j < 16; ++j) {
            float dx = x[j] - px;
            float dy = y[j] - py;
            float dz = z[j] - pz;
            float d = dx * dx + dy * dy;     // contract off: plain mul/add
            d = d + dz * dz;
            float nd = fminf(dist[j], d);
            dist[j] = nd;
            if (nd > bd) { bd = nd; bi = j * 256 + t; bx = x[j]; by = y[j]; bz = z[j]; }
        }
#pragma unroll
        for (int off = 32; off > 0; off >>= 1) {
            float od = __shfl_xor(bd, off);
            int   oi = __shfl_xor(bi, off);
            float ox = __shfl_xor(bx, off);
            float oy = __shfl_xor(by, off);
            float oz = __shfl_xor(bz, off);
            if (od > bd || (od == bd && oi < bi)) { bd = od; bi = oi; bx = ox; by = oy; bz = oz; }
        }
        int par = it & 1;
        if (lane == 0) {
            sd[par][wid] = bd; si[par][wid] = bi;
            sx[par][wid] = bx; sy[par][wid] = by; sz[par][wid] = bz;
        }
        __syncthreads();
        float cd = sd[par][0]; int ci = si[par][0];
        float cx = sx[par][0], cy = sy[par][0], cz = sz[par][0];
#pragma unroll
        for (int w = 1; w < 4; ++w) {
            float od = sd[par][w]; int oi = si[par][w];
            if (od > cd || (od == cd && oi < ci)) {
                cd = od; ci = oi; cx = sx[par][w]; cy = sy[par][w]; cz = sz[par][w];
            }
        }
        px = cx; py = cy; pz = cz;
        if (t == 0) {
            size_t ao = ((size_t)g * M_ + it) * 3;
            anchors[ao + 0] = px; anchors[ao + 1] = py; anchors[ao + 2] = pz;
            out_xyz[ao + 0] = px; out_xyz[ao + 1] = py; out_xyz[ao + 2] = pz;
        }
    }
}

// ---------------------------------------------------------------------------
// Kernel 2: Ball query (unchanged from passing version).
// ---------------------------------------------------------------------------
__global__ __launch_bounds__(256) void ballq_kernel(const float* __restrict__ xyzs,
                                                    const float* __restrict__ anchors,
                                                    int* __restrict__ widx)
{
#pragma clang fp contract(off)
    const float R2 = 0.0225f;
    const int wave = (blockIdx.x << 2) + (threadIdx.x >> 6);
    const int lane = threadIdx.x & 63;
    const int m   = wave % M_;
    const int gd  = wave / M_;      // g*3 + dti
    const int dti = gd % 3;
    const int g   = gd / 3;
    const int b = g >> 4, f = g & 15;
    int tn = 2 * f + dti - 1;
    if (tn < 0) tn = 0;
    const float* nb = xyzs + ((size_t)(b * T_ + tn) * N_) * 3;
    const float* aw = anchors + ((size_t)g * M_ + m) * 3;
    const float ax = aw[0], ay = aw[1], az = aw[2];

    __shared__ int sbuf[4][K_];
    int* buf = sbuf[threadIdx.x >> 6];

    int filled = 0;
    for (int itb = 0; itb < 64 && filled < K_; ++itb) {
        int p = itb * 64 + lane;
        float dx = nb[p * 3 + 0] - ax;
        float dy = nb[p * 3 + 1] - ay;
        float dz = nb[p * 3 + 2] - az;
        float d2 = dx * dx + dy * dy;
        d2 = d2 + dz * dz;
        bool valid = d2 < R2;
        unsigned long long mask = __ballot(valid);
        if (valid) {
            int slot = filled + __popcll(mask & ((1ULL << lane) - 1ULL));
            if (slot < K_) buf[slot] = p;
        }
        filled += __popcll(mask);
    }
    __syncthreads();
    if (lane < K_) {
        int first = (filled > 0) ? buf[0] : 0;
        int v = (lane < filled) ? buf[lane] : first;
        widx[(size_t)wave * K_ + lane] = v;
    }
}

// ---------------------------------------------------------------------------
// Kernel 3: MLP via MFMA. One block per (g,m). GEMM D[96][128] = A[96][64] x
// B[64][128] where A = h1 (3 dt x 32 k rows), B = Wm^T. bf16 hi/lo split,
// 3-term MFMA. XOR-swizzled LDS (T2) for conflict-free ds_read_b128 frags.
// ---------------------------------------------------------------------------
__global__ __launch_bounds__(256) void mlp_kernel(const float* __restrict__ xyzs,
                                                  const float* __restrict__ Wd,
                                                  const short* __restrict__ Bhi_g,
                                                  const short* __restrict__ Blo_g,
                                                  const float* __restrict__ anchors,
                                                  const int* __restrict__ widx,
                                                  float* __restrict__ out_feat)
{
    const int t  = threadIdx.x;
    const int gm = blockIdx.x;
    const int g  = gm >> 7;
    const int m  = gm & 127;
    const int b = g >> 4, f = g & 15;

    __shared__ __align__(16) short Bhi[C1_ * C0_];   // 16 KB
    __shared__ __align__(16) short Blo[C1_ * C0_];   // 16 KB
    __shared__ __align__(16) short Ahi[96 * C0_];    // 12 KB
    __shared__ __align__(16) short Alo[96 * C0_];    // 12 KB
    __shared__ float d4s[96][4];
    __shared__ float wd_s[C0_ * 4];
    __shared__ float pm[6][C1_];

    // --- phase 1: copy pre-split Wm into LDS (already swizzled), stage Wd,
    //     and compute d4 (displacements) for all 96 (dt,k) rows.
    {
#pragma unroll
        for (int rep = 0; rep < 4; ++rep) {
            int e0 = (rep * 256 + t) * 8;
            *reinterpret_cast<short8*>(&Bhi[e0]) = *reinterpret_cast<const short8*>(&Bhi_g[e0]);
            *reinterpret_cast<short8*>(&Blo[e0]) = *reinterpret_cast<const short8*>(&Blo_g[e0]);
        }
        wd_s[t] = Wd[t];
        if (t < 96) {
            int dti = t >> 5, k = t & 31;
            int tn = 2 * f + dti - 1;
            if (tn < 0) tn = 0;
            const float* nb = xyzs + ((size_t)(b * T_ + tn) * N_) * 3;
            const float* aw = anchors + ((size_t)g * M_ + m) * 3;
            int idx = widx[((size_t)(g * 3 + dti) * M_ + m) * K_ + k];
            d4s[t][0] = nb[idx * 3 + 0] - aw[0];
            d4s[t][1] = nb[idx * 3 + 1] - aw[1];
            d4s[t][2] = nb[idx * 3 + 2] - aw[2];
            d4s[t][3] = (float)(dti - 1);
        }
    }
    __syncthreads();

    // --- phase 2: h1 = relu(Wd . d4), split to bf16 hi/lo, store swizzled.
    //     768 (row, i-chunk) tasks: r = id>>3 (0..95), u = id&7 (i = u*8..+7)
#pragma unroll
    for (int rep = 0; rep < 3; ++rep) {
        int id = rep * 256 + t;
        int r = id >> 3, u = id & 7;
        float a0 = d4s[r][0], a1 = d4s[r][1], a2 = d4s[r][2], a3 = d4s[r][3];
        short8 hv, lv;
#pragma unroll
        for (int e = 0; e < 8; ++e) {
            int i = u * 8 + e;
            float s = a0 * wd_s[i * 4 + 0] + a1 * wd_s[i * 4 + 1]
                    + a2 * wd_s[i * 4 + 2] + a3 * wd_s[i * 4 + 3];
            s = fmaxf(s, 0.0f);
            short h = f2bf(s);
            short l = f2bf(s - bf2f(h));
            hv[e] = h; lv[e] = l;
        }
        int off = r * C0_ + ((u ^ (r & 7)) << 3);
        *reinterpret_cast<short8*>(&Ahi[off]) = hv;
        *reinterpret_cast<short8*>(&Alo[off]) = lv;
    }
    __syncthreads();

    // --- phase 3: MFMA. wave w: M-half wm (3 tiles of 16), N-half wn (4 tiles)
    const int lane = t & 63;
    const int w   = t >> 6;
    const int wm = w & 1, wn = w >> 1;
    const int row0 = lane & 15;
    const int kg   = lane >> 4;

    f32x4 acc[3][4];
#pragma unroll
    for (int mt = 0; mt < 3; ++mt)
#pragma unroll
        for (int nt = 0; nt < 4; ++nt) {
            acc[mt][nt][0] = 0.f; acc[mt][nt][1] = 0.f;
            acc[mt][nt][2] = 0.f; acc[mt][nt][3] = 0.f;
        }

#pragma unroll
    for (int ks = 0; ks < 2; ++ks) {
        int chunk = ks * 4 + kg;
        short8 ah[3], al[3], bh[4], bl[4];
#pragma unroll
        for (int mt = 0; mt < 3; ++mt) {
            int r = wm * 48 + mt * 16 + row0;
            int off = r * C0_ + ((chunk ^ (r & 7)) << 3);
            ah[mt] = *reinterpret_cast<const short8*>(&Ahi[off]);
            al[mt] = *reinterpret_cast<const short8*>(&Alo[off]);
        }
#pragma unroll
        for (int nt = 0; nt < 4; ++nt) {
            int o = wn * 64 + nt * 16 + row0;
            int off = o * C0_ + ((chunk ^ (o & 7)) << 3);
            bh[nt] = *reinterpret_cast<const short8*>(&Bhi[off]);
            bl[nt] = *reinterpret_cast<const short8*>(&Blo[off]);
        }
#pragma unroll
        for (int mt = 0; mt < 3; ++mt)
#pragma unroll
            for (int nt = 0; nt < 4; ++nt) {
                acc[mt][nt] = __builtin_amdgcn_mfma_f32_16x16x32_bf16(ah[mt], bh[nt], acc[mt][nt], 0, 0, 0);
                acc[mt][nt] = __builtin_amdgcn_mfma_f32_16x16x32_bf16(ah[mt], bl[nt], acc[mt][nt], 0, 0, 0);
                acc[mt][nt] = __builtin_amdgcn_mfma_f32_16x16x32_bf16(al[mt], bh[nt], acc[mt][nt], 0, 0, 0);
            }
    }

    // --- epilogue: per tile, relu+max over the 16 rows (4 regs + shfl over
    //     the 4 lane-groups), write per-Mtile partial to pm, then sum dts.
#pragma unroll
    for (int mt = 0; mt < 3; ++mt)
#pragma unroll
        for (int nt = 0; nt < 4; ++nt) {
            f32x4 a = acc[mt][nt];
            float mv = fmaxf(fmaxf(a[0], a[1]), fmaxf(a[2], a[3]));
            mv = fmaxf(mv, 0.0f);
            mv = fmaxf(mv, __shfl_xor(mv, 16));
            mv = fmaxf(mv, __shfl_xor(mv, 32));
            if (lane < 16) pm[wm * 3 + mt][wn * 64 + nt * 16 + lane] = mv;
        }
    __syncthreads();

    if (t < C1_) {
        float fs = fmaxf(pm[0][t], pm[1][t])
                 + fmaxf(pm[2][t], pm[3][t])
                 + fmaxf(pm[4][t], pm[5][t]);
        out_feat[((size_t)g * C1_ + t) * M_ + m] = fs;
    }
}

// ---------------------------------------------------------------------------
extern "C" void kernel_launch(void* const* d_in, const int* in_sizes, int n_in,
                              void* d_out, int out_size, void* d_ws, size_t ws_size,
                              hipStream_t stream)
{
    (void)in_sizes; (void)n_in; (void)out_size; (void)ws_size;
    const float* xyzs = (const float*)d_in[0];
    const float* Wd   = (const float*)d_in[1];
    const float* Wm   = (const float*)d_in[2];
    float* out = (float*)d_out;

    char* ws = (char*)d_ws;
    short* Bhi_g   = (short*)ws;                              // 16 KB
    short* Blo_g   = (short*)(ws + 16384);                    // 16 KB
    float* anchors = (float*)(ws + 32768);                    // G*M*3 floats
    int*   widx    = (int*)(ws + 32768 + (size_t)G_ * M_ * 3 * 4);

    float* out_xyz  = out;                 // (B,F,M,3) = (G,M,3)
    float* out_feat = out + G_ * M_ * 3;   // (B,F,C1,M) = (G,C1,M)

    hipLaunchKernelGGL(wsplit_kernel, dim3(4),                 dim3(256), 0, stream, Wm, Bhi_g, Blo_g);
    hipLaunchKernelGGL(fps_kernel,    dim3(G_),                dim3(256), 0, stream, xyzs, anchors, out_xyz);
    hipLaunchKernelGGL(ballq_kernel,  dim3(G_ * 3 * M_ / 4),   dim3(256), 0, stream, xyzs, anchors, widx);
    hipLaunchKernelGGL(mlp_kernel,    dim3(G_ * M_),           dim3(256), 0, stream, xyzs, Wd, Bhi_g, Blo_g, anchors, widx, out_feat);
}

// Round 3
// 334.375 us; speedup vs baseline: 1.3980x; 1.3040x over previous
//
#include <hip/hip_runtime.h>
#include <stdint.h>

#define B_   4
#define T_   32
#define N_   4096
#define F_   16
#define G_   64      // B*F
#define M_   128
#define K_   32
#define C0_  64
#define C1_  128

typedef short  short8 __attribute__((ext_vector_type(8)));
typedef float  f32x4  __attribute__((ext_vector_type(4)));

static __device__ __forceinline__ short f2bf(float x) {
    union { float f; unsigned u; } v; v.f = x;
    unsigned r = (v.u + 0x7FFFu + ((v.u >> 16) & 1u)) >> 16;
    return (short)r;
}
static __device__ __forceinline__ float bf2f(short h) {
    union { float f; unsigned u; } v; v.u = ((unsigned)(unsigned short)h) << 16;
    return v.f;
}

// ---------------------------------------------------------------------------
// Kernel 0: split Wm (fp32 [128][64]) into hi/lo bf16, stored in the swizzled
// LDS layout mlp uses: off = o*64 + ((chunk ^ (o&7))<<3) + e, chunk = i/8.
// ---------------------------------------------------------------------------
__global__ __launch_bounds__(256) void wsplit_kernel(const float* __restrict__ Wm,
                                                     short* __restrict__ Bhi_g,
                                                     short* __restrict__ Blo_g)
{
    int id = blockIdx.x * 256 + threadIdx.x;   // 0..1023
    int o = id >> 3, c = id & 7;
    const float* wp = Wm + o * C0_ + c * 8;
    short8 hv, lv;
#pragma unroll
    for (int e = 0; e < 8; ++e) {
        float v = wp[e];
        short h = f2bf(v);
        short l = f2bf(v - bf2f(h));
        hv[e] = h; lv[e] = l;
    }
    int dst = o * C0_ + ((c ^ (o & 7)) << 3);
    *reinterpret_cast<short8*>(&Bhi_g[dst]) = hv;
    *reinterpret_cast<short8*>(&Blo_g[dst]) = lv;
}

// ---------------------------------------------------------------------------
// Kernel 1: FPS. 512 threads/block (2 waves/SIMD for latency hiding).
// No global traffic inside the loop (anchors buffered in registers, written
// coalesced at the end). Argmax via packed u64 key: bits(d)<<32 | (4095-i)
// -- monotonic for d>=0, ties pick smaller index (= reference semantics).
// Winner coords fetched from an LDS coordinate cache (broadcast read).
// Bit-exact fp32 distance math (contract off, same eval order as reference).
// ---------------------------------------------------------------------------
__global__ __launch_bounds__(512) void fps_kernel(const float* __restrict__ xyzs,
                                                  float* __restrict__ anchors,
                                                  float* __restrict__ out_xyz)
{
#pragma clang fp contract(off)
    const int g = blockIdx.x;
    const int b = g >> 4, f = g & 15;
    const float* base = xyzs + ((size_t)(b * T_ + 2 * f) * N_) * 3;
    const int t = threadIdx.x;       // 0..511
    const int lane = t & 63;
    const int wid = t >> 6;          // 0..7

    __shared__ float cxs[N_], cys[N_], czs[N_];           // 48 KB coord cache
    __shared__ unsigned long long sred[2][8];

    float x[8], y[8], z[8], dist[8];
#pragma unroll
    for (int j = 0; j < 8; ++j) {
        int p = j * 512 + t;
        float xx = base[p * 3 + 0];
        float yy = base[p * 3 + 1];
        float zz = base[p * 3 + 2];
        x[j] = xx; y[j] = yy; z[j] = zz; dist[j] = 1e10f;
        cxs[p] = xx; cys[p] = yy; czs[p] = zz;
    }

    float px = base[0], py = base[1], pz = base[2];   // anchor 0 = point 0
    float rx = 0.f, ry = 0.f, rz = 0.f;               // my buffered anchor
    if (t == 0) { rx = px; ry = py; rz = pz; }
    __syncthreads();                                   // coord cache ready

    for (int it = 1; it < M_; ++it) {
        float bd = -1.0f; int bi = 0;
#pragma unroll
        for (int j = 0; j < 8; ++j) {
            float dx = x[j] - px;
            float dy = y[j] - py;
            float dz = z[j] - pz;
            float d = dx * dx + dy * dy;    // contract off: plain mul/add
            d = d + dz * dz;
            float nd = fminf(dist[j], d);
            dist[j] = nd;
            if (nd > bd) { bd = nd; bi = j * 512 + t; }  // ascending p: first max kept
        }
        unsigned long long key =
            ((unsigned long long)__float_as_uint(bd) << 32) | (unsigned)(N_ - 1 - bi);
#pragma unroll
        for (int off = 32; off > 0; off >>= 1) {
            unsigned long long ok = __shfl_xor(key, off);
            key = (ok > key) ? ok : key;
        }
        const int par = it & 1;
        if (lane == 0) sred[par][wid] = key;
        __syncthreads();
        unsigned long long ck = sred[par][0];
#pragma unroll
        for (int w = 1; w < 8; ++w) {
            unsigned long long ok = sred[par][w];
            ck = (ok > ck) ? ok : ck;
        }
        int ci = (N_ - 1) - (int)(ck & 0xFFFFFFFFu);
        px = cxs[ci]; py = cys[ci]; pz = czs[ci];      // LDS broadcast read
        if (t == it) { rx = px; ry = py; rz = pz; }
    }

    if (t < M_) {
        size_t ao = ((size_t)g * M_ + t) * 3;
        anchors[ao + 0] = rx; anchors[ao + 1] = ry; anchors[ao + 2] = rz;
        out_xyz[ao + 0] = rx; out_xyz[ao + 1] = ry; out_xyz[ao + 2] = rz;
    }
}

// ---------------------------------------------------------------------------
// Kernel 2: Ball query. One wave per (g, dt, m). First-K-in-radius with
// PointNet++ fill semantics, index order preserved via ballot prefix-pack.
// ---------------------------------------------------------------------------
__global__ __launch_bounds__(256) void ballq_kernel(const float* __restrict__ xyzs,
                                                    const float* __restrict__ anchors,
                                                    int* __restrict__ widx)
{
#pragma clang fp contract(off)
    const float R2 = 0.0225f;
    const int wave = (blockIdx.x << 2) + (threadIdx.x >> 6);
    const int lane = threadIdx.x & 63;
    const int m   = wave % M_;
    const int gd  = wave / M_;      // g*3 + dti
    const int dti = gd % 3;
    const int g   = gd / 3;
    const int b = g >> 4, f = g & 15;
    int tn = 2 * f + dti - 1;
    if (tn < 0) tn = 0;
    const float* nb = xyzs + ((size_t)(b * T_ + tn) * N_) * 3;
    const float* aw = anchors + ((size_t)g * M_ + m) * 3;
    const float ax = aw[0], ay = aw[1], az = aw[2];

    __shared__ int sbuf[4][K_];
    int* buf = sbuf[threadIdx.x >> 6];

    int filled = 0;
    for (int itb = 0; itb < 64 && filled < K_; ++itb) {
        int p = itb * 64 + lane;
        float dx = nb[p * 3 + 0] - ax;
        float dy = nb[p * 3 + 1] - ay;
        float dz = nb[p * 3 + 2] - az;
        float d2 = dx * dx + dy * dy;
        d2 = d2 + dz * dz;
        bool valid = d2 < R2;
        unsigned long long mask = __ballot(valid);
        if (valid) {
            int slot = filled + __popcll(mask & ((1ULL << lane) - 1ULL));
            if (slot < K_) buf[slot] = p;
        }
        filled += __popcll(mask);
    }
    __syncthreads();
    if (lane < K_) {
        int first = (filled > 0) ? buf[0] : 0;
        int v = (lane < filled) ? buf[lane] : first;
        widx[(size_t)wave * K_ + lane] = v;
    }
}

// ---------------------------------------------------------------------------
// Kernel 3: MLP via MFMA. One block per (g,m). D[96][128] = A[96][64]xB[64][128]
// A = relu(Wd.d4) rows (3 dt x 32 k), B = Wm^T. 2-term bf16 MFMA:
// Ah*Bh + Ah*Bl (Alo dropped: adds <~3e-3 error, threshold 3.25e-2).
// XOR-swizzled LDS for conflict-free ds_read_b128 fragments.
// ---------------------------------------------------------------------------
__global__ __launch_bounds__(256) void mlp_kernel(const float* __restrict__ xyzs,
                                                  const float* __restrict__ Wd,
                                                  const short* __restrict__ Bhi_g,
                                                  const short* __restrict__ Blo_g,
                                                  const float* __restrict__ anchors,
                                                  const int* __restrict__ widx,
                                                  float* __restrict__ out_feat)
{
    const int t  = threadIdx.x;
    const int gm = blockIdx.x;
    const int g  = gm >> 7;
    const int m  = gm & 127;
    const int b = g >> 4, f = g & 15;

    __shared__ __align__(16) short Bhi[C1_ * C0_];   // 16 KB
    __shared__ __align__(16) short Blo[C1_ * C0_];   // 16 KB
    __shared__ __align__(16) short Ahi[96 * C0_];    // 12 KB
    __shared__ float d4s[96][4];
    __shared__ float wd_s[C0_ * 4];
    __shared__ float pm[6][C1_];

    // --- phase 1: stage pre-split/swizzled Wm, Wd; gather d4 rows.
    {
#pragma unroll
        for (int rep = 0; rep < 4; ++rep) {
            int e0 = (rep * 256 + t) * 8;
            *reinterpret_cast<short8*>(&Bhi[e0]) = *reinterpret_cast<const short8*>(&Bhi_g[e0]);
            *reinterpret_cast<short8*>(&Blo[e0]) = *reinterpret_cast<const short8*>(&Blo_g[e0]);
        }
        wd_s[t] = Wd[t];
        if (t < 96) {
            int dti = t >> 5, k = t & 31;
            int tn = 2 * f + dti - 1;
            if (tn < 0) tn = 0;
            const float* nb = xyzs + ((size_t)(b * T_ + tn) * N_) * 3;
            const float* aw = anchors + ((size_t)g * M_ + m) * 3;
            int idx = widx[((size_t)(g * 3 + dti) * M_ + m) * K_ + k];
            d4s[t][0] = nb[idx * 3 + 0] - aw[0];
            d4s[t][1] = nb[idx * 3 + 1] - aw[1];
            d4s[t][2] = nb[idx * 3 + 2] - aw[2];
            d4s[t][3] = (float)(dti - 1);
        }
    }
    __syncthreads();

    // --- phase 2: h1 = relu(Wd . d4) -> bf16, swizzled store.
#pragma unroll
    for (int rep = 0; rep < 3; ++rep) {
        int id = rep * 256 + t;
        int r = id >> 3, u = id & 7;
        float a0 = d4s[r][0], a1 = d4s[r][1], a2 = d4s[r][2], a3 = d4s[r][3];
        short8 hv;
#pragma unroll
        for (int e = 0; e < 8; ++e) {
            int i = u * 8 + e;
            float s = a0 * wd_s[i * 4 + 0] + a1 * wd_s[i * 4 + 1]
                    + a2 * wd_s[i * 4 + 2] + a3 * wd_s[i * 4 + 3];
            hv[e] = f2bf(fmaxf(s, 0.0f));
        }
        int off = r * C0_ + ((u ^ (r & 7)) << 3);
        *reinterpret_cast<short8*>(&Ahi[off]) = hv;
    }
    __syncthreads();

    // --- phase 3: MFMA. wave w: M-half wm (3 tiles), N-half wn (4 tiles).
    const int lane = t & 63;
    const int w   = t >> 6;
    const int wm = w & 1, wn = w >> 1;
    const int row0 = lane & 15;
    const int kg   = lane >> 4;

    f32x4 acc[3][4];
#pragma unroll
    for (int mt = 0; mt < 3; ++mt)
#pragma unroll
        for (int nt = 0; nt < 4; ++nt) {
            acc[mt][nt][0] = 0.f; acc[mt][nt][1] = 0.f;
            acc[mt][nt][2] = 0.f; acc[mt][nt][3] = 0.f;
        }

#pragma unroll
    for (int ks = 0; ks < 2; ++ks) {
        int chunk = ks * 4 + kg;
        short8 ah[3], bh[4], bl[4];
#pragma unroll
        for (int mt = 0; mt < 3; ++mt) {
            int r = wm * 48 + mt * 16 + row0;
            ah[mt] = *reinterpret_cast<const short8*>(&Ahi[r * C0_ + ((chunk ^ (r & 7)) << 3)]);
        }
#pragma unroll
        for (int nt = 0; nt < 4; ++nt) {
            int o = wn * 64 + nt * 16 + row0;
            int off = o * C0_ + ((chunk ^ (o & 7)) << 3);
            bh[nt] = *reinterpret_cast<const short8*>(&Bhi[off]);
            bl[nt] = *reinterpret_cast<const short8*>(&Blo[off]);
        }
#pragma unroll
        for (int mt = 0; mt < 3; ++mt)
#pragma unroll
            for (int nt = 0; nt < 4; ++nt) {
                acc[mt][nt] = __builtin_amdgcn_mfma_f32_16x16x32_bf16(ah[mt], bh[nt], acc[mt][nt], 0, 0, 0);
                acc[mt][nt] = __builtin_amdgcn_mfma_f32_16x16x32_bf16(ah[mt], bl[nt], acc[mt][nt], 0, 0, 0);
            }
    }

    // --- epilogue: relu+max over 16 rows per tile, then sum over dt.
#pragma unroll
    for (int mt = 0; mt < 3; ++mt)
#pragma unroll
        for (int nt = 0; nt < 4; ++nt) {
            f32x4 a = acc[mt][nt];
            float mv = fmaxf(fmaxf(a[0], a[1]), fmaxf(a[2], a[3]));
            mv = fmaxf(mv, 0.0f);
            mv = fmaxf(mv, __shfl_xor(mv, 16));
            mv = fmaxf(mv, __shfl_xor(mv, 32));
            if (lane < 16) pm[wm * 3 + mt][wn * 64 + nt * 16 + lane] = mv;
        }
    __syncthreads();

    if (t < C1_) {
        float fs = fmaxf(pm[0][t], pm[1][t])
                 + fmaxf(pm[2][t], pm[3][t])
                 + fmaxf(pm[4][t], pm[5][t]);
        out_feat[((size_t)g * C1_ + t) * M_ + m] = fs;
    }
}

// ---------------------------------------------------------------------------
extern "C" void kernel_launch(void* const* d_in, const int* in_sizes, int n_in,
                              void* d_out, int out_size, void* d_ws, size_t ws_size,
                              hipStream_t stream)
{
    (void)in_sizes; (void)n_in; (void)out_size; (void)ws_size;
    const float* xyzs = (const float*)d_in[0];
    const float* Wd   = (const float*)d_in[1];
    const float* Wm   = (const float*)d_in[2];
    float* out = (float*)d_out;

    char* ws = (char*)d_ws;
    short* Bhi_g   = (short*)ws;                              // 16 KB
    short* Blo_g   = (short*)(ws + 16384);                    // 16 KB
    float* anchors = (float*)(ws + 32768);                    // G*M*3 floats
    int*   widx    = (int*)(ws + 32768 + (size_t)G_ * M_ * 3 * 4);

    float* out_xyz  = out;                 // (B,F,M,3) = (G,M,3)
    float* out_feat = out + G_ * M_ * 3;   // (B,F,C1,M) = (G,C1,M)

    hipLaunchKernelGGL(wsplit_kernel, dim3(4),               dim3(256), 0, stream, Wm, Bhi_g, Blo_g);
    hipLaunchKernelGGL(fps_kernel,    dim3(G_),              dim3(512), 0, stream, xyzs, anchors, out_xyz);
    hipLaunchKernelGGL(ballq_kernel,  dim3(G_ * 3 * M_ / 4), dim3(256), 0, stream, xyzs, anchors, widx);
    hipLaunchKernelGGL(mlp_kernel,    dim3(G_ * M_),         dim3(256), 0, stream, xyzs, Wd, Bhi_g, Blo_g, anchors, widx, out_feat);
}

// Round 4
// 258.033 us; speedup vs baseline: 1.8116x; 1.2959x over previous
//
#include <hip/hip_runtime.h>
#include <stdint.h>

#define B_   4
#define T_   32
#define N_   4096
#define F_   16
#define G_   64      // B*F
#define M_   128
#define K_   32
#define C0_  64
#define C1_  128

typedef short  short8 __attribute__((ext_vector_type(8)));
typedef float  f32x4  __attribute__((ext_vector_type(4)));

static __device__ __forceinline__ short f2bf(float x) {
    union { float f; unsigned u; } v; v.f = x;
    unsigned r = (v.u + 0x7FFFu + ((v.u >> 16) & 1u)) >> 16;
    return (short)r;
}
static __device__ __forceinline__ float bf2f(short h) {
    union { float f; unsigned u; } v; v.u = ((unsigned)(unsigned short)h) << 16;
    return v.f;
}

// u64 max-combine helper: DPP row_shr:<n> on both halves (old=0 is identity
// for unsigned max; invalid source lanes receive 0).
template<int CTRL>
static __device__ __forceinline__ unsigned long long dpp_u64(unsigned long long v) {
    int lo = __builtin_amdgcn_update_dpp(0, (int)(unsigned)v,         CTRL, 0xF, 0xF, false);
    int hi = __builtin_amdgcn_update_dpp(0, (int)(unsigned)(v >> 32), CTRL, 0xF, 0xF, false);
    return ((unsigned long long)(unsigned)hi << 32) | (unsigned)lo;
}

// ---------------------------------------------------------------------------
// Kernel 0: split Wm (fp32 [128][64]) into hi/lo bf16, PLAIN layout
// (off = o*64 + i). mlp loads B-fragments straight from global into regs.
// ---------------------------------------------------------------------------
__global__ __launch_bounds__(256) void wsplit_kernel(const float* __restrict__ Wm,
                                                     short* __restrict__ Bhi_g,
                                                     short* __restrict__ Blo_g)
{
    int id = blockIdx.x * 256 + threadIdx.x;   // 0..1023
    int o = id >> 3, c = id & 7;
    const float* wp = Wm + o * C0_ + c * 8;
    short8 hv, lv;
#pragma unroll
    for (int e = 0; e < 8; ++e) {
        float v = wp[e];
        short h = f2bf(v);
        short l = f2bf(v - bf2f(h));
        hv[e] = h; lv[e] = l;
    }
    int dst = o * C0_ + c * 8;
    *reinterpret_cast<short8*>(&Bhi_g[dst]) = hv;
    *reinterpret_cast<short8*>(&Blo_g[dst]) = lv;
}

// ---------------------------------------------------------------------------
// Kernel 1: FPS. 512 threads/block. Packed u64 key argmax; wave reduce via
// 4x DPP row_shr (VALU-speed) + shfl_xor(16,32); lane 63 publishes. No global
// traffic in the loop; anchors buffered per-thread, coalesced write at end.
// Bit-exact fp32 distances (contract off, reference eval order).
// ---------------------------------------------------------------------------
__global__ __launch_bounds__(512) void fps_kernel(const float* __restrict__ xyzs,
                                                  float* __restrict__ anchors,
                                                  float* __restrict__ out_xyz)
{
#pragma clang fp contract(off)
    const int g = blockIdx.x;
    const int b = g >> 4, f = g & 15;
    const float* base = xyzs + ((size_t)(b * T_ + 2 * f) * N_) * 3;
    const int t = threadIdx.x;       // 0..511
    const int lane = t & 63;
    const int wid = t >> 6;          // 0..7

    __shared__ float cxs[N_], cys[N_], czs[N_];           // 48 KB coord cache
    __shared__ unsigned long long sred[2][8];

    float x[8], y[8], z[8], dist[8];
#pragma unroll
    for (int j = 0; j < 8; ++j) {
        int p = j * 512 + t;
        float xx = base[p * 3 + 0];
        float yy = base[p * 3 + 1];
        float zz = base[p * 3 + 2];
        x[j] = xx; y[j] = yy; z[j] = zz; dist[j] = 1e10f;
        cxs[p] = xx; cys[p] = yy; czs[p] = zz;
    }

    float px = base[0], py = base[1], pz = base[2];   // anchor 0 = point 0
    float rx = 0.f, ry = 0.f, rz = 0.f;               // my buffered anchor
    if (t == 0) { rx = px; ry = py; rz = pz; }
    __syncthreads();                                   // coord cache ready

    for (int it = 1; it < M_; ++it) {
        float bd = -1.0f; int bi = 0;
#pragma unroll
        for (int j = 0; j < 8; ++j) {
            float dx = x[j] - px;
            float dy = y[j] - py;
            float dz = z[j] - pz;
            float d = dx * dx + dy * dy;    // contract off: plain mul/add
            d = d + dz * dz;
            float nd = fminf(dist[j], d);
            dist[j] = nd;
            if (nd > bd) { bd = nd; bi = j * 512 + t; }  // ascending p: first max kept
        }
        unsigned long long key =
            ((unsigned long long)__float_as_uint(bd) << 32) | (unsigned)(N_ - 1 - bi);
        unsigned long long k2;
        k2 = dpp_u64<0x111>(key); key = (k2 > key) ? k2 : key;   // row_shr:1
        k2 = dpp_u64<0x112>(key); key = (k2 > key) ? k2 : key;   // row_shr:2
        k2 = dpp_u64<0x114>(key); key = (k2 > key) ? k2 : key;   // row_shr:4
        k2 = dpp_u64<0x118>(key); key = (k2 > key) ? k2 : key;   // row_shr:8
        k2 = __shfl_xor(key, 16); key = (k2 > key) ? k2 : key;   // lanes %16==15 hold pair-row max
        k2 = __shfl_xor(key, 32); key = (k2 > key) ? k2 : key;   // lane 63 holds wave max
        const int par = it & 1;
        if (lane == 63) sred[par][wid] = key;
        __syncthreads();
        unsigned long long ck = sred[par][0];
#pragma unroll
        for (int w = 1; w < 8; ++w) {
            unsigned long long ok = sred[par][w];
            ck = (ok > ck) ? ok : ck;
        }
        int ci = (N_ - 1) - (int)(ck & 0xFFFFFFFFu);
        px = cxs[ci]; py = cys[ci]; pz = czs[ci];      // LDS broadcast read
        if (t == it) { rx = px; ry = py; rz = pz; }
    }

    if (t < M_) {
        size_t ao = ((size_t)g * M_ + t) * 3;
        anchors[ao + 0] = rx; anchors[ao + 1] = ry; anchors[ao + 2] = rz;
        out_xyz[ao + 0] = rx; out_xyz[ao + 1] = ry; out_xyz[ao + 2] = rz;
    }
}

// ---------------------------------------------------------------------------
// Kernel 2: Ball query, chunked. One wave per (g, dt, m). 8 iterations' loads
// + ballots issued together (pipelined), then VALU-only prefix-pack; exit
// check per chunk. Semantics identical to first-K-in-radius + fill.
// ---------------------------------------------------------------------------
__global__ __launch_bounds__(256) void ballq_kernel(const float* __restrict__ xyzs,
                                                    const float* __restrict__ anchors,
                                                    int* __restrict__ widx)
{
#pragma clang fp contract(off)
    const float R2 = 0.0225f;
    const int wave = (blockIdx.x << 2) + (threadIdx.x >> 6);
    const int lane = threadIdx.x & 63;
    const int m   = wave % M_;
    const int gd  = wave / M_;      // g*3 + dti
    const int dti = gd % 3;
    const int g   = gd / 3;
    const int b = g >> 4, f = g & 15;
    int tn = 2 * f + dti - 1;
    if (tn < 0) tn = 0;
    const float* nb = xyzs + ((size_t)(b * T_ + tn) * N_) * 3;
    const float* aw = anchors + ((size_t)g * M_ + m) * 3;
    const float ax = aw[0], ay = aw[1], az = aw[2];

    __shared__ int sbuf[4][K_];
    int* buf = sbuf[threadIdx.x >> 6];
    const unsigned long long lanebit = 1ULL << lane;

    int filled = 0;
    for (int cb = 0; cb < 8 && filled < K_; ++cb) {
        unsigned long long mk[8];
#pragma unroll
        for (int u = 0; u < 8; ++u) {
            int p = cb * 512 + u * 64 + lane;
            float dx = nb[p * 3 + 0] - ax;
            float dy = nb[p * 3 + 1] - ay;
            float dz = nb[p * 3 + 2] - az;
            float d2 = dx * dx + dy * dy;
            d2 = d2 + dz * dz;
            mk[u] = __ballot(d2 < R2);
        }
#pragma unroll
        for (int u = 0; u < 8; ++u) {
            if (mk[u] & lanebit) {
                int slot = filled + __popcll(mk[u] & (lanebit - 1ULL));
                if (slot < K_) buf[slot] = cb * 512 + u * 64 + lane;
            }
            filled += __popcll(mk[u]);
        }
    }
    __syncthreads();
    if (lane < K_) {
        int first = (filled > 0) ? buf[0] : 0;
        int v = (lane < filled) ? buf[lane] : first;
        widx[(size_t)wave * K_ + lane] = v;
    }
}

// ---------------------------------------------------------------------------
// Kernel 3: MLP via MFMA, B-in-registers. One block per (g, m-pair): 4096
// blocks, 256 thr (4 waves). Wave = (m_local, N-half): 6 M-tiles x 4 N-tiles,
// 96 MFMA. B-frags (Wm hi/lo, plain layout) loaded global->reg at entry; only
// A (h1, 24 KB) staged in LDS (XOR-swizzled). Outputs packed via 1 KB LDS ->
// coalesced float2 stores.
// ---------------------------------------------------------------------------
__global__ __launch_bounds__(256, 2) void mlp_kernel(const float* __restrict__ xyzs,
                                                     const float* __restrict__ Wd,
                                                     const short* __restrict__ Bhi_g,
                                                     const short* __restrict__ Blo_g,
                                                     const float* __restrict__ anchors,
                                                     const int* __restrict__ widx,
                                                     float* __restrict__ out_feat)
{
    const int t   = threadIdx.x;
    const int blk = blockIdx.x;          // G * 64
    const int g   = blk >> 6;
    const int m0  = (blk & 63) * 2;
    const int b = g >> 4, f = g & 15;

    const int lane = t & 63;
    const int w    = t >> 6;             // 0..3
    const int wml  = w & 1;              // m_local
    const int wn   = w >> 1;             // N-half (64 cols)
    const int row0 = lane & 15;
    const int kg   = lane >> 4;

    __shared__ __align__(16) short Ahi[192 * C0_];   // 24 KB
    __shared__ float wd_s[C0_ * 4];                  // 1 KB
    __shared__ float pmf[2][C1_];                    // 1 KB

    // --- B fragments from global (plain layout), issued immediately.
    short8 bh[4][2], bl[4][2];   // [nt][ks]
#pragma unroll
    for (int nt = 0; nt < 4; ++nt) {
        int o = wn * 64 + nt * 16 + row0;
#pragma unroll
        for (int ks = 0; ks < 2; ++ks) {
            int off = o * C0_ + (ks * 4 + kg) * 8;
            bh[nt][ks] = *reinterpret_cast<const short8*>(&Bhi_g[off]);
            bl[nt][ks] = *reinterpret_cast<const short8*>(&Blo_g[off]);
        }
    }

    wd_s[t] = Wd[t];

    // --- gather: thread t < 192 owns row t = ml*96 + dti*32 + k.
    float dx = 0.f, dy = 0.f, dz = 0.f, dt4 = 0.f;
    if (t < 192) {
        int ml  = (t >= 96) ? 1 : 0;
        int rr  = t - ml * 96;
        int dti = rr >> 5, k = rr & 31;
        int m   = m0 + ml;
        int tn  = 2 * f + dti - 1;
        if (tn < 0) tn = 0;
        const float* nb = xyzs + ((size_t)(b * T_ + tn) * N_) * 3;
        int idx = widx[((size_t)(g * 3 + dti) * M_ + m) * K_ + k];
        const float* aw = anchors + ((size_t)g * M_ + m) * 3;
        dx = nb[idx * 3 + 0] - aw[0];
        dy = nb[idx * 3 + 1] - aw[1];
        dz = nb[idx * 3 + 2] - aw[2];
        dt4 = (float)(dti - 1);
    }
    __syncthreads();   // wd_s ready

    // --- h1 = relu(Wd . d4) -> bf16, XOR-swizzled LDS rows.
    if (t < 192) {
#pragma unroll
        for (int u = 0; u < 8; ++u) {
            short8 hv;
#pragma unroll
            for (int e = 0; e < 8; ++e) {
                float4 wv = *reinterpret_cast<const float4*>(&wd_s[(u * 8 + e) * 4]);
                float s = dx * wv.x + dy * wv.y + dz * wv.z + dt4 * wv.w;
                hv[e] = f2bf(fmaxf(s, 0.0f));
            }
            *reinterpret_cast<short8*>(&Ahi[t * C0_ + ((u ^ (t & 7)) << 3)]) = hv;
        }
    }
    __syncthreads();

    // --- MFMA: D[rows 96 of wml][cols 64 of wn].
    f32x4 acc[6][4];
#pragma unroll
    for (int mt = 0; mt < 6; ++mt)
#pragma unroll
        for (int nt = 0; nt < 4; ++nt) {
            acc[mt][nt][0] = 0.f; acc[mt][nt][1] = 0.f;
            acc[mt][nt][2] = 0.f; acc[mt][nt][3] = 0.f;
        }

#pragma unroll
    for (int ks = 0; ks < 2; ++ks) {
        int chunk = ks * 4 + kg;
        short8 ah[6];
#pragma unroll
        for (int mt = 0; mt < 6; ++mt) {
            int r = wml * 96 + mt * 16 + row0;
            ah[mt] = *reinterpret_cast<const short8*>(&Ahi[r * C0_ + ((chunk ^ (r & 7)) << 3)]);
        }
#pragma unroll
        for (int mt = 0; mt < 6; ++mt)
#pragma unroll
            for (int nt = 0; nt < 4; ++nt) {
                acc[mt][nt] = __builtin_amdgcn_mfma_f32_16x16x32_bf16(ah[mt], bh[nt][ks], acc[mt][nt], 0, 0, 0);
                acc[mt][nt] = __builtin_amdgcn_mfma_f32_16x16x32_bf16(ah[mt], bl[nt][ks], acc[mt][nt], 0, 0, 0);
            }
    }

    // --- epilogue: per (dti, col) max over 32 k-rows (2 tiles x 4 regs x
    //     4 lane-groups), relu, sum dts; pack both m's -> float2 stores.
#pragma unroll
    for (int nt = 0; nt < 4; ++nt) {
        float fs = 0.f;
#pragma unroll
        for (int dti = 0; dti < 3; ++dti) {
            f32x4 a0 = acc[dti * 2 + 0][nt];
            f32x4 a1 = acc[dti * 2 + 1][nt];
            float mv = fmaxf(fmaxf(fmaxf(a0[0], a0[1]), fmaxf(a0[2], a0[3])),
                             fmaxf(fmaxf(a1[0], a1[1]), fmaxf(a1[2], a1[3])));
            mv = fmaxf(mv, 0.0f);
            mv = fmaxf(mv, __shfl_xor(mv, 16));
            mv = fmaxf(mv, __shfl_xor(mv, 32));
            fs += mv;   // dt order -1,0,+1 = reference accumulation order
        }
        if (lane < 16) pmf[wml][wn * 64 + nt * 16 + lane] = fs;
    }
    __syncthreads();

    if (t < C1_) {
        float2 v = make_float2(pmf[0][t], pmf[1][t]);
        *reinterpret_cast<float2*>(&out_feat[((size_t)g * C1_ + t) * M_ + m0]) = v;
    }
}

// ---------------------------------------------------------------------------
extern "C" void kernel_launch(void* const* d_in, const int* in_sizes, int n_in,
                              void* d_out, int out_size, void* d_ws, size_t ws_size,
                              hipStream_t stream)
{
    (void)in_sizes; (void)n_in; (void)out_size; (void)ws_size;
    const float* xyzs = (const float*)d_in[0];
    const float* Wd   = (const float*)d_in[1];
    const float* Wm   = (const float*)d_in[2];
    float* out = (float*)d_out;

    char* ws = (char*)d_ws;
    short* Bhi_g   = (short*)ws;                              // 16 KB
    short* Blo_g   = (short*)(ws + 16384);                    // 16 KB
    float* anchors = (float*)(ws + 32768);                    // G*M*3 floats
    int*   widx    = (int*)(ws + 32768 + (size_t)G_ * M_ * 3 * 4);

    float* out_xyz  = out;                 // (B,F,M,3) = (G,M,3)
    float* out_feat = out + G_ * M_ * 3;   // (B,F,C1,M) = (G,C1,M)

    hipLaunchKernelGGL(wsplit_kernel, dim3(4),               dim3(256), 0, stream, Wm, Bhi_g, Blo_g);
    hipLaunchKernelGGL(fps_kernel,    dim3(G_),              dim3(512), 0, stream, xyzs, anchors, out_xyz);
    hipLaunchKernelGGL(ballq_kernel,  dim3(G_ * 3 * M_ / 4), dim3(256), 0, stream, xyzs, anchors, widx);
    hipLaunchKernelGGL(mlp_kernel,    dim3(G_ * 64),         dim3(256), 0, stream, xyzs, Wd, Bhi_g, Blo_g, anchors, widx, out_feat);
}